// Round 1
// 1213.438 us; speedup vs baseline: 1.0294x; 1.0294x over previous
//
#include <hip/hip_runtime.h>

typedef unsigned short u16;
typedef __bf16 bf16x8 __attribute__((ext_vector_type(8)));
typedef float floatx4 __attribute__((ext_vector_type(4)));
typedef u16 u16x8 __attribute__((ext_vector_type(8)));

// Problem: B=4, S=8192, D=1024, H=16 -> 64 attention blocks of [512 x 1024]
// M_total = 32768 rows.

__device__ __forceinline__ u16 f2bf(float f) {
  union { float f; unsigned u; } x; x.f = f;
  unsigned r = x.u + 0x7FFFu + ((x.u >> 16) & 1u);
  return (u16)(r >> 16);
}

__device__ __forceinline__ void async16(const u16* g, u16* l) {
  __builtin_amdgcn_global_load_lds((const __attribute__((address_space(1))) void*)g,
                                   (__attribute__((address_space(3))) void*)l,
                                   16, 0, 0);
}

// ---------------------------------------------------------------------------
// Weight convert+transpose: W [K=1024][N=1024] f32 -> Wt [N][K] bf16
// ---------------------------------------------------------------------------
__global__ __launch_bounds__(256) void wconv_t(const float* __restrict__ wq,
                                               const float* __restrict__ wk,
                                               const float* __restrict__ wv,
                                               u16* __restrict__ dst0) {
  const float* src = blockIdx.z == 0 ? wq : (blockIdx.z == 1 ? wk : wv);
  u16* dst = dst0 + (size_t)blockIdx.z * 1024 * 1024;
  __shared__ float t[32][33];
  int k0 = blockIdx.y * 32, n0 = blockIdx.x * 32;
  int tid = threadIdx.x;
  int row = tid >> 3, c4 = (tid & 7) * 4;
  float4 v = *(const float4*)&src[(size_t)(k0 + row) * 1024 + n0 + c4];
  t[row][c4 + 0] = v.x; t[row][c4 + 1] = v.y; t[row][c4 + 2] = v.z; t[row][c4 + 3] = v.w;
  __syncthreads();
  ushort4 u;
  u.x = f2bf(t[c4 + 0][row]);
  u.y = f2bf(t[c4 + 1][row]);
  u.z = f2bf(t[c4 + 2][row]);
  u.w = f2bf(t[c4 + 3][row]);
  *(ushort4*)&dst[(size_t)(n0 + row) * 1024 + k0 + c4] = u;
}

// w_final is used as context @ w_final.T -> already [N][K]; plain convert.
__global__ __launch_bounds__(256) void wconv(const float* __restrict__ w, u16* __restrict__ dst) {
  size_t i = ((size_t)blockIdx.x * 256 + threadIdx.x) * 4;
  float4 v = *(const float4*)&w[i];
  ushort4 u; u.x = f2bf(v.x); u.y = f2bf(v.y); u.z = f2bf(v.z); u.w = f2bf(v.w);
  *(ushort4*)&dst[i] = u;
}

// ---------------------------------------------------------------------------
// Cast q/k/v f32 -> bf16 (contiguous dst, z selects array). 8 elems/thread.
// ---------------------------------------------------------------------------
__global__ __launch_bounds__(256) void cast_bf16(const float* __restrict__ q,
                                                 const float* __restrict__ k,
                                                 const float* __restrict__ v,
                                                 u16* __restrict__ dst0) {
  const float* src = blockIdx.z == 0 ? q : (blockIdx.z == 1 ? k : v);
  u16* dst = dst0 + (size_t)blockIdx.z * 33554432;
  size_t i = ((size_t)blockIdx.x * 256 + threadIdx.x) * 8;
  float4 a = *(const float4*)&src[i];
  float4 b = *(const float4*)&src[i + 4];
  u16x8 o;
  o[0] = f2bf(a.x); o[1] = f2bf(a.y); o[2] = f2bf(a.z); o[3] = f2bf(a.w);
  o[4] = f2bf(b.x); o[5] = f2bf(b.y); o[6] = f2bf(b.z); o[7] = f2bf(b.w);
  *(u16x8*)&dst[i] = o;
}

// ---------------------------------------------------------------------------
// Transpose V: per block z: V[512][1024] bf16 -> Vt[1024][512] bf16
// ---------------------------------------------------------------------------
__global__ __launch_bounds__(256) void transpose_v(const u16* __restrict__ V,
                                                   u16* __restrict__ Vt) {
  __shared__ u16 t[64][65];
  const u16* src = V + (size_t)blockIdx.z * 512 * 1024;
  u16* dst = Vt + (size_t)blockIdx.z * 1024 * 512;
  int s0 = blockIdx.y * 64, d0 = blockIdx.x * 64;
  int tid = threadIdx.x;
#pragma unroll
  for (int i = 0; i < 4; ++i) {
    int row = i * 16 + (tid >> 4);
    int c4 = (tid & 15) * 4;
    ushort4 v = *(const ushort4*)&src[(size_t)(s0 + row) * 1024 + d0 + c4];
    t[row][c4 + 0] = v.x; t[row][c4 + 1] = v.y; t[row][c4 + 2] = v.z; t[row][c4 + 3] = v.w;
  }
  __syncthreads();
#pragma unroll
  for (int i = 0; i < 4; ++i) {
    int row = i * 16 + (tid >> 4);   // d index within tile
    int c4 = (tid & 15) * 4;         // s index within tile
    ushort4 u;
    u.x = t[c4 + 0][row]; u.y = t[c4 + 1][row]; u.z = t[c4 + 2][row]; u.w = t[c4 + 3][row];
    *(ushort4*)&dst[(size_t)(d0 + row) * 512 + s0 + c4] = u;
  }
}

// ---------------------------------------------------------------------------
// GEMM, gemm_bt pattern: C[m][n] = sum_k A[m][k] * B[n][k], A and B bf16.
// 128x128 tile, BK=32, 4 waves (2x2), each wave 4x4 tiles of 16x16x32 MFMA.
// Staging via global_load_lds width=16 for BOTH operands.
// OMODE: 0 = bf16 store, 1 = fp32*scale store (scores), 2 = fp32 +bias+residual.
// XCD-aware bijective swizzle applied when gridDim.z==1 and nwg%8==0.
// ---------------------------------------------------------------------------
template <int OMODE>
__global__ __launch_bounds__(256) void gemm_bt(
    const u16* __restrict__ Ap, const u16* __restrict__ Bp, void* __restrict__ Cp,
    int K, int lda, int ldb, int ldc,
    long long sA, long long sB, long long sC,
    const float* __restrict__ res, const float* __restrict__ bias, float scale) {
  __shared__ u16 Asm[128 * 32];
  __shared__ u16 Bsm[128 * 32];

  const int tid = threadIdx.x;
  const int wave = tid >> 6, lane = tid & 63;
  const int wm = wave >> 1, wn = wave & 1;
  const int quad = lane >> 4, r16 = lane & 15;
  const long long z = blockIdx.z;

  int bx = blockIdx.x, by = blockIdx.y;
  if (gridDim.z == 1) {
    unsigned nwg = gridDim.x * gridDim.y;
    if ((nwg & 7u) == 0u) {
      unsigned bid = (unsigned)by * gridDim.x + bx;
      unsigned nb = (bid & 7u) * (nwg >> 3) + (bid >> 3);
      bx = nb % gridDim.x;
      by = nb / gridDim.x;
    }
  }
  const size_t m0 = (size_t)by * 128;
  const size_t n0 = (size_t)bx * 128;

  const u16* Ab = Ap + (size_t)(z * sA);
  const u16* Bb = Bp + (size_t)(z * sB);
  floatx4 acc[4][4] = {};

  for (int k0 = 0; k0 < K; k0 += 32) {
#pragma unroll
    for (int c = 0; c < 2; ++c) {
      int chunk = c * 4 + wave;
      int row = chunk * 16 + (lane >> 2);
      int col = (lane & 3) * 8;
      async16(Ab + (m0 + row) * (size_t)lda + k0 + col, &Asm[chunk * 512]);
    }
#pragma unroll
    for (int c = 0; c < 2; ++c) {
      int chunk = c * 4 + wave;
      int row = chunk * 16 + (lane >> 2);
      int col = (lane & 3) * 8;
      async16(Bb + (n0 + row) * (size_t)ldb + k0 + col, &Bsm[chunk * 512]);
    }
    __syncthreads();

    bf16x8 af[4], bfr[4];
#pragma unroll
    for (int i = 0; i < 4; ++i)
      af[i] = *(const bf16x8*)&Asm[(wm * 64 + i * 16 + r16) * 32 + quad * 8];
#pragma unroll
    for (int j = 0; j < 4; ++j)
      bfr[j] = *(const bf16x8*)&Bsm[(wn * 64 + j * 16 + r16) * 32 + quad * 8];
#pragma unroll
    for (int i = 0; i < 4; ++i)
#pragma unroll
      for (int j = 0; j < 4; ++j)
        acc[i][j] = __builtin_amdgcn_mfma_f32_16x16x32_bf16(af[i], bfr[j], acc[i][j], 0, 0, 0);
    __syncthreads();
  }

#pragma unroll
  for (int i = 0; i < 4; ++i) {
    size_t row = m0 + wm * 64 + i * 16 + quad * 4;
#pragma unroll
    for (int j = 0; j < 4; ++j) {
      size_t col = n0 + wn * 64 + j * 16 + r16;
#pragma unroll
      for (int r = 0; r < 4; ++r) {
        size_t idx = (row + r) * (size_t)ldc + col;
        if constexpr (OMODE == 0) {
          ((u16*)Cp)[(size_t)(z * sC) + idx] = f2bf(acc[i][j][r]);
        } else if constexpr (OMODE == 1) {
          ((float*)Cp)[(size_t)(z * sC) + idx] = acc[i][j][r] * scale;
        } else {
          float xv = acc[i][j][r] + bias[col] + res[idx];
          ((float*)Cp)[idx] = xv;
        }
      }
    }
  }
}

// ---------------------------------------------------------------------------
// Softmax in place over rows of 512 (one wave per row); also emits bf16 P.
// ---------------------------------------------------------------------------
__global__ __launch_bounds__(256) void softmax_k(float* __restrict__ attn,
                                                 u16* __restrict__ Pb) {
  size_t row = (size_t)blockIdx.x * 4 + (threadIdx.x >> 6);
  int lane = threadIdx.x & 63;
  float* p = attn + row * 512 + lane * 8;
  float4 a = *(const float4*)p;
  float4 b = *(const float4*)(p + 4);
  float m = fmaxf(fmaxf(fmaxf(a.x, a.y), fmaxf(a.z, a.w)),
                  fmaxf(fmaxf(b.x, b.y), fmaxf(b.z, b.w)));
#pragma unroll
  for (int off = 32; off >= 1; off >>= 1) m = fmaxf(m, __shfl_xor(m, off));
  float e[8];
  e[0] = __expf(a.x - m); e[1] = __expf(a.y - m); e[2] = __expf(a.z - m); e[3] = __expf(a.w - m);
  e[4] = __expf(b.x - m); e[5] = __expf(b.y - m); e[6] = __expf(b.z - m); e[7] = __expf(b.w - m);
  float s = e[0] + e[1] + e[2] + e[3] + e[4] + e[5] + e[6] + e[7];
#pragma unroll
  for (int off = 32; off >= 1; off >>= 1) s += __shfl_xor(s, off);
  float inv = 1.0f / s;
  float o[8];
#pragma unroll
  for (int i = 0; i < 8; ++i) o[i] = e[i] * inv;
  float4 oa, ob;
  oa.x = o[0]; oa.y = o[1]; oa.z = o[2]; oa.w = o[3];
  ob.x = o[4]; ob.y = o[5]; ob.z = o[6]; ob.w = o[7];
  *(float4*)p = oa;
  *(float4*)(p + 4) = ob;
  u16x8 pb;
#pragma unroll
  for (int i = 0; i < 8; ++i) pb[i] = f2bf(o[i]);
  *(u16x8*)&Pb[row * 512 + lane * 8] = pb;
}

// ---------------------------------------------------------------------------
// LayerNorm rows of 1024 (one block of 256 per row): out = (x-mean)*rstd*g + b
// ---------------------------------------------------------------------------
__global__ __launch_bounds__(256) void layernorm_k(const float* __restrict__ x,
                                                   const float* __restrict__ gamma,
                                                   const float* __restrict__ beta,
                                                   float* __restrict__ out) {
  size_t row = blockIdx.x;
  int tid = threadIdx.x, lane = tid & 63, wave = tid >> 6;
  float4 v = *(const float4*)&x[row * 1024 + tid * 4];
  float s = v.x + v.y + v.z + v.w;
  float q = v.x * v.x + v.y * v.y + v.z * v.z + v.w * v.w;
#pragma unroll
  for (int off = 32; off >= 1; off >>= 1) {
    s += __shfl_xor(s, off);
    q += __shfl_xor(q, off);
  }
  __shared__ float ss[4], qq[4];
  if (lane == 0) { ss[wave] = s; qq[wave] = q; }
  __syncthreads();
  s = ss[0] + ss[1] + ss[2] + ss[3];
  q = qq[0] + qq[1] + qq[2] + qq[3];
  float mean = s * (1.0f / 1024.0f);
  float var = q * (1.0f / 1024.0f) - mean * mean;
  float rstd = rsqrtf(var + 1e-5f);
  float4 g = *(const float4*)&gamma[tid * 4];
  float4 be = *(const float4*)&beta[tid * 4];
  float4 o;
  o.x = (v.x - mean) * rstd * g.x + be.x;
  o.y = (v.y - mean) * rstd * g.y + be.y;
  o.z = (v.z - mean) * rstd * g.z + be.z;
  o.w = (v.w - mean) * rstd * g.w + be.w;
  *(float4*)&out[row * 1024 + tid * 4] = o;
}

// ---------------------------------------------------------------------------
extern "C" void kernel_launch(void* const* d_in, const int* in_sizes, int n_in,
                              void* d_out, int out_size, void* d_ws, size_t ws_size,
                              hipStream_t stream) {
  const float* query = (const float*)d_in[0];
  const float* key   = (const float*)d_in[1];
  const float* value = (const float*)d_in[2];
  const float* wq    = (const float*)d_in[3];
  const float* wk    = (const float*)d_in[4];
  const float* wv    = (const float*)d_in[5];
  const float* wfin  = (const float*)d_in[6];
  const float* bfin  = (const float*)d_in[7];
  const float* gamma = (const float*)d_in[8];
  const float* beta  = (const float*)d_in[9];

  // Workspace layout (bytes), high-water 328 MB with aliasing:
  //   0..8M    : WQT WKT WVT WF (bf16 weights)
  //   8M..72M  : Qin (dead after Q-proj) -> Vb (dead after transpose) -> CTX
  //   72M..136M: Kin (dead after K-proj) -> VTb
  //   136M..200M: Vin (dead after V-proj) -> Pb (32MB bf16 P)
  //   200M..328M: Qb+Kb (dead after scores) -> X (f32 [32768][1024])
  char* ws = (char*)d_ws;
  u16* WQT = (u16*)ws;                     // 2 MB each, [N][K] bf16
  u16* WKT = WQT + 1024 * 1024;
  u16* WVT = WKT + 1024 * 1024;
  u16* WF  = WVT + 1024 * 1024;
  u16* Qin = (u16*)(ws + 8388608);         // 64 MB each, contiguous for cast z-stride
  u16* Kin = Qin + 33554432;
  u16* Vin = Kin + 33554432;
  u16* Qb  = (u16*)(ws + 209715200);       // 200M
  u16* Kb  = Qb + 33554432;                // 264M..328M
  u16* Vb  = Qin;                          // alias: Qin dead after Q-proj
  u16* VTb = Kin;                          // alias: Kin dead after K-proj
  u16* Pb  = Vin;                          // alias: Vin dead after V-proj (32MB used)
  u16* CTX = Qin;                          // alias: Vb dead after transpose_v
  float* X = (float*)(ws + 209715200);     // alias Qb+Kb (dead after scores), 128 MB

  float* out  = (float*)d_out;             // [32768][1024] f32
  float* attn = out + 33554432;            // [64][512][512] f32 (output 1)

  dim3 blk(256);

  wconv_t<<<dim3(32, 32, 3), blk, 0, stream>>>(wq, wk, wv, WQT);
  wconv<<<dim3(1024), blk, 0, stream>>>(wfin, WF);
  cast_bf16<<<dim3(16384, 1, 3), blk, 0, stream>>>(query, key, value, Qin);

  // Projections: [32768,1024] = A(bf16) x Wt(bf16), async16 both operands.
  gemm_bt<0><<<dim3(8, 256, 1), blk, 0, stream>>>(Qin, WQT, Qb, 1024, 1024, 1024, 1024,
                                                  0, 0, 0, nullptr, nullptr, 1.0f);
  gemm_bt<0><<<dim3(8, 256, 1), blk, 0, stream>>>(Kin, WKT, Kb, 1024, 1024, 1024, 1024,
                                                  0, 0, 0, nullptr, nullptr, 1.0f);
  gemm_bt<0><<<dim3(8, 256, 1), blk, 0, stream>>>(Vin, WVT, Vb, 1024, 1024, 1024, 1024,
                                                  0, 0, 0, nullptr, nullptr, 1.0f);

  transpose_v<<<dim3(16, 8, 64), blk, 0, stream>>>(Vb, VTb);

  // Scores: per block z: S = Q_blk x K_blk^T * 0.125 -> d_out attn region (f32)
  gemm_bt<1><<<dim3(4, 4, 64), blk, 0, stream>>>(Qb, Kb, attn, 1024, 1024, 1024, 512,
                                                 524288, 524288, 262144,
                                                 nullptr, nullptr, 0.125f);

  softmax_k<<<dim3(8192), blk, 0, stream>>>(attn, Pb);

  // PV: ctx = P(bf16) x Vt -> bf16
  gemm_bt<0><<<dim3(8, 4, 64), blk, 0, stream>>>(Pb, VTb, CTX, 512, 512, 512, 1024,
                                                 262144, 524288, 524288,
                                                 nullptr, nullptr, 1.0f);

  // Final: x = ctx x WF^T(bt) + b_final + residual(query) -> f32
  gemm_bt<2><<<dim3(8, 256, 1), blk, 0, stream>>>(CTX, WF, X, 1024, 1024, 1024, 1024,
                                                  0, 0, 0, query, bfin, 1.0f);

  layernorm_k<<<dim3(32768), blk, 0, stream>>>(X, gamma, beta, out);
}

// Round 2
// 1179.133 us; speedup vs baseline: 1.0594x; 1.0291x over previous
//
#include <hip/hip_runtime.h>

typedef unsigned short u16;
typedef __bf16 bf16x8 __attribute__((ext_vector_type(8)));
typedef float floatx4 __attribute__((ext_vector_type(4)));
typedef u16 u16x8 __attribute__((ext_vector_type(8)));

// Problem: B=4, S=8192, D=1024, H=16 -> 64 attention blocks of [512 x 1024]
// M_total = 32768 rows.

__device__ __forceinline__ u16 f2bf(float f) {
  union { float f; unsigned u; } x; x.f = f;
  unsigned r = x.u + 0x7FFFu + ((x.u >> 16) & 1u);
  return (u16)(r >> 16);
}

__device__ __forceinline__ void async16(const u16* g, u16* l) {
  __builtin_amdgcn_global_load_lds((const __attribute__((address_space(1))) void*)g,
                                   (__attribute__((address_space(3))) void*)l,
                                   16, 0, 0);
}

// ---------------------------------------------------------------------------
// Weight convert+transpose: W [K=1024][N=1024] f32 -> Wt [N][K] bf16
// ---------------------------------------------------------------------------
__global__ __launch_bounds__(256) void wconv_t(const float* __restrict__ wq,
                                               const float* __restrict__ wk,
                                               const float* __restrict__ wv,
                                               u16* __restrict__ dst0) {
  const float* src = blockIdx.z == 0 ? wq : (blockIdx.z == 1 ? wk : wv);
  u16* dst = dst0 + (size_t)blockIdx.z * 1024 * 1024;
  __shared__ float t[32][33];
  int k0 = blockIdx.y * 32, n0 = blockIdx.x * 32;
  int tid = threadIdx.x;
  int row = tid >> 3, c4 = (tid & 7) * 4;
  float4 v = *(const float4*)&src[(size_t)(k0 + row) * 1024 + n0 + c4];
  t[row][c4 + 0] = v.x; t[row][c4 + 1] = v.y; t[row][c4 + 2] = v.z; t[row][c4 + 3] = v.w;
  __syncthreads();
  ushort4 u;
  u.x = f2bf(t[c4 + 0][row]);
  u.y = f2bf(t[c4 + 1][row]);
  u.z = f2bf(t[c4 + 2][row]);
  u.w = f2bf(t[c4 + 3][row]);
  *(ushort4*)&dst[(size_t)(n0 + row) * 1024 + k0 + c4] = u;
}

// w_final is used as context @ w_final.T -> already [N][K]; plain convert.
__global__ __launch_bounds__(256) void wconv(const float* __restrict__ w, u16* __restrict__ dst) {
  size_t i = ((size_t)blockIdx.x * 256 + threadIdx.x) * 4;
  float4 v = *(const float4*)&w[i];
  ushort4 u; u.x = f2bf(v.x); u.y = f2bf(v.y); u.z = f2bf(v.z); u.w = f2bf(v.w);
  *(ushort4*)&dst[i] = u;
}

// ---------------------------------------------------------------------------
// Cast q/k/v f32 -> bf16 (contiguous dst, z selects array). 8 elems/thread.
// ---------------------------------------------------------------------------
__global__ __launch_bounds__(256) void cast_bf16(const float* __restrict__ q,
                                                 const float* __restrict__ k,
                                                 const float* __restrict__ v,
                                                 u16* __restrict__ dst0) {
  const float* src = blockIdx.z == 0 ? q : (blockIdx.z == 1 ? k : v);
  u16* dst = dst0 + (size_t)blockIdx.z * 33554432;
  size_t i = ((size_t)blockIdx.x * 256 + threadIdx.x) * 8;
  float4 a = *(const float4*)&src[i];
  float4 b = *(const float4*)&src[i + 4];
  u16x8 o;
  o[0] = f2bf(a.x); o[1] = f2bf(a.y); o[2] = f2bf(a.z); o[3] = f2bf(a.w);
  o[4] = f2bf(b.x); o[5] = f2bf(b.y); o[6] = f2bf(b.z); o[7] = f2bf(b.w);
  *(u16x8*)&dst[i] = o;
}

// ---------------------------------------------------------------------------
// Transpose V: per block z: V[512][1024] bf16 -> Vt[1024][512] bf16
// ---------------------------------------------------------------------------
__global__ __launch_bounds__(256) void transpose_v(const u16* __restrict__ V,
                                                   u16* __restrict__ Vt) {
  __shared__ u16 t[64][65];
  const u16* src = V + (size_t)blockIdx.z * 512 * 1024;
  u16* dst = Vt + (size_t)blockIdx.z * 1024 * 512;
  int s0 = blockIdx.y * 64, d0 = blockIdx.x * 64;
  int tid = threadIdx.x;
#pragma unroll
  for (int i = 0; i < 4; ++i) {
    int row = i * 16 + (tid >> 4);
    int c4 = (tid & 15) * 4;
    ushort4 v = *(const ushort4*)&src[(size_t)(s0 + row) * 1024 + d0 + c4];
    t[row][c4 + 0] = v.x; t[row][c4 + 1] = v.y; t[row][c4 + 2] = v.z; t[row][c4 + 3] = v.w;
  }
  __syncthreads();
#pragma unroll
  for (int i = 0; i < 4; ++i) {
    int row = i * 16 + (tid >> 4);   // d index within tile
    int c4 = (tid & 15) * 4;         // s index within tile
    ushort4 u;
    u.x = t[c4 + 0][row]; u.y = t[c4 + 1][row]; u.z = t[c4 + 2][row]; u.w = t[c4 + 3][row];
    *(ushort4*)&dst[(size_t)(d0 + row) * 512 + s0 + c4] = u;
  }
}

// ---------------------------------------------------------------------------
// GEMM, gemm_bt pattern: C[m][n] = sum_k A[m][k] * B[n][k], A and B bf16.
// 128x128 tile, BK=32, 4 waves (2x2), each wave 4x4 tiles of 16x16x32 MFMA.
// Staging via global_load_lds width=16 for BOTH operands; staging pointers
// hoisted out of the K-loop (+32/iter) to keep VGPR count low (occupancy).
// OMODE: 0 = bf16 store, 1 = fp32*scale store (scores), 2 = fp32 +bias+residual.
// XCD-aware bijective swizzle over the FULL (x,y,z) grid; requires pow2 gx,gy
// and nwg%8==0 (all launches here satisfy this).
// ---------------------------------------------------------------------------
template <int OMODE>
__global__ __launch_bounds__(256) void gemm_bt(
    const u16* __restrict__ Ap, const u16* __restrict__ Bp, void* __restrict__ Cp,
    int K, int lda, int ldb, int ldc,
    int sA, int sB, int sC,
    const float* __restrict__ res, const float* __restrict__ bias, float scale) {
  __shared__ u16 Asm[128 * 32];
  __shared__ u16 Bsm[128 * 32];

  const int tid = threadIdx.x;
  const int wave = tid >> 6, lane = tid & 63;
  const int wm = wave >> 1, wn = wave & 1;
  const int quad = lane >> 4, r16 = lane & 15;

  // XCD-aware bijective swizzle (pow2 de-linearize; no integer division).
  const unsigned gx = gridDim.x, gy = gridDim.y;
  const unsigned nwg = gx * gy * gridDim.z;
  unsigned bid = (blockIdx.z * gy + blockIdx.y) * gx + blockIdx.x;
  unsigned nb = (bid & 7u) * (nwg >> 3) + (bid >> 3);
  const unsigned bx = nb & (gx - 1u);
  nb >>= __builtin_ctz(gx);
  const unsigned by = nb & (gy - 1u);
  nb >>= __builtin_ctz(gy);
  const unsigned bz = nb;

  const unsigned m0 = by * 128u;
  const unsigned n0 = bx * 128u;

  const u16* Ab = Ap + (size_t)bz * (unsigned)sA;
  const u16* Bb = Bp + (size_t)bz * (unsigned)sB;

  // Staging addresses: chunk = {wave, wave+4}; lane covers 16 rows x 32 cols.
  const int srow = lane >> 2;          // 0..15
  const int scol = (lane & 3) * 8;     // 0,8,16,24
  const u16* ga = Ab + (size_t)((m0 + wave * 16 + srow) * (unsigned)lda + scol);
  const u16* gb = Bb + (size_t)((n0 + wave * 16 + srow) * (unsigned)ldb + scol);
  const size_t stepA = (size_t)64 * (unsigned)lda;   // chunk c=1 row offset
  const size_t stepB = (size_t)64 * (unsigned)ldb;
  u16* la = &Asm[wave * 512];           // wave-uniform LDS base (lane x 16B auto)
  u16* lb = &Bsm[wave * 512];

  floatx4 acc[4][4] = {};

  for (int k0 = 0; k0 < K; k0 += 32) {
    async16(ga, la);
    async16(ga + stepA, la + 2048);
    async16(gb, lb);
    async16(gb + stepB, lb + 2048);
    ga += 32;
    gb += 32;
    __syncthreads();

    bf16x8 af[4], bfr[4];
#pragma unroll
    for (int i = 0; i < 4; ++i)
      af[i] = *(const bf16x8*)&Asm[(wm * 64 + i * 16 + r16) * 32 + quad * 8];
#pragma unroll
    for (int j = 0; j < 4; ++j)
      bfr[j] = *(const bf16x8*)&Bsm[(wn * 64 + j * 16 + r16) * 32 + quad * 8];
#pragma unroll
    for (int i = 0; i < 4; ++i)
#pragma unroll
      for (int j = 0; j < 4; ++j)
        acc[i][j] = __builtin_amdgcn_mfma_f32_16x16x32_bf16(af[i], bfr[j], acc[i][j], 0, 0, 0);
    __syncthreads();
  }

#pragma unroll
  for (int i = 0; i < 4; ++i) {
    unsigned row = m0 + wm * 64 + i * 16 + quad * 4;
#pragma unroll
    for (int j = 0; j < 4; ++j) {
      unsigned col = n0 + wn * 64 + j * 16 + r16;
#pragma unroll
      for (int r = 0; r < 4; ++r) {
        unsigned idx = (row + r) * (unsigned)ldc + col;
        if constexpr (OMODE == 0) {
          ((u16*)Cp)[(size_t)bz * (unsigned)sC + idx] = f2bf(acc[i][j][r]);
        } else if constexpr (OMODE == 1) {
          ((float*)Cp)[(size_t)bz * (unsigned)sC + idx] = acc[i][j][r] * scale;
        } else {
          float xv = acc[i][j][r] + bias[col] + res[idx];
          ((float*)Cp)[idx] = xv;
        }
      }
    }
  }
}

// ---------------------------------------------------------------------------
// Softmax in place over rows of 512 (one wave per row); also emits bf16 P.
// ---------------------------------------------------------------------------
__global__ __launch_bounds__(256) void softmax_k(float* __restrict__ attn,
                                                 u16* __restrict__ Pb) {
  size_t row = (size_t)blockIdx.x * 4 + (threadIdx.x >> 6);
  int lane = threadIdx.x & 63;
  float* p = attn + row * 512 + lane * 8;
  float4 a = *(const float4*)p;
  float4 b = *(const float4*)(p + 4);
  float m = fmaxf(fmaxf(fmaxf(a.x, a.y), fmaxf(a.z, a.w)),
                  fmaxf(fmaxf(b.x, b.y), fmaxf(b.z, b.w)));
#pragma unroll
  for (int off = 32; off >= 1; off >>= 1) m = fmaxf(m, __shfl_xor(m, off));
  float e[8];
  e[0] = __expf(a.x - m); e[1] = __expf(a.y - m); e[2] = __expf(a.z - m); e[3] = __expf(a.w - m);
  e[4] = __expf(b.x - m); e[5] = __expf(b.y - m); e[6] = __expf(b.z - m); e[7] = __expf(b.w - m);
  float s = e[0] + e[1] + e[2] + e[3] + e[4] + e[5] + e[6] + e[7];
#pragma unroll
  for (int off = 32; off >= 1; off >>= 1) s += __shfl_xor(s, off);
  float inv = 1.0f / s;
  float o[8];
#pragma unroll
  for (int i = 0; i < 8; ++i) o[i] = e[i] * inv;
  float4 oa, ob;
  oa.x = o[0]; oa.y = o[1]; oa.z = o[2]; oa.w = o[3];
  ob.x = o[4]; ob.y = o[5]; ob.z = o[6]; ob.w = o[7];
  *(float4*)p = oa;
  *(float4*)(p + 4) = ob;
  u16x8 pb;
#pragma unroll
  for (int i = 0; i < 8; ++i) pb[i] = f2bf(o[i]);
  *(u16x8*)&Pb[row * 512 + lane * 8] = pb;
}

// ---------------------------------------------------------------------------
// LayerNorm rows of 1024 (one block of 256 per row): out = (x-mean)*rstd*g + b
// ---------------------------------------------------------------------------
__global__ __launch_bounds__(256) void layernorm_k(const float* __restrict__ x,
                                                   const float* __restrict__ gamma,
                                                   const float* __restrict__ beta,
                                                   float* __restrict__ out) {
  size_t row = blockIdx.x;
  int tid = threadIdx.x, lane = tid & 63, wave = tid >> 6;
  float4 v = *(const float4*)&x[row * 1024 + tid * 4];
  float s = v.x + v.y + v.z + v.w;
  float q = v.x * v.x + v.y * v.y + v.z * v.z + v.w * v.w;
#pragma unroll
  for (int off = 32; off >= 1; off >>= 1) {
    s += __shfl_xor(s, off);
    q += __shfl_xor(q, off);
  }
  __shared__ float ss[4], qq[4];
  if (lane == 0) { ss[wave] = s; qq[wave] = q; }
  __syncthreads();
  s = ss[0] + ss[1] + ss[2] + ss[3];
  q = qq[0] + qq[1] + qq[2] + qq[3];
  float mean = s * (1.0f / 1024.0f);
  float var = q * (1.0f / 1024.0f) - mean * mean;
  float rstd = rsqrtf(var + 1e-5f);
  float4 g = *(const float4*)&gamma[tid * 4];
  float4 be = *(const float4*)&beta[tid * 4];
  float4 o;
  o.x = (v.x - mean) * rstd * g.x + be.x;
  o.y = (v.y - mean) * rstd * g.y + be.y;
  o.z = (v.z - mean) * rstd * g.z + be.z;
  o.w = (v.w - mean) * rstd * g.w + be.w;
  *(float4*)&out[row * 1024 + tid * 4] = o;
}

// ---------------------------------------------------------------------------
extern "C" void kernel_launch(void* const* d_in, const int* in_sizes, int n_in,
                              void* d_out, int out_size, void* d_ws, size_t ws_size,
                              hipStream_t stream) {
  const float* query = (const float*)d_in[0];
  const float* key   = (const float*)d_in[1];
  const float* value = (const float*)d_in[2];
  const float* wq    = (const float*)d_in[3];
  const float* wk    = (const float*)d_in[4];
  const float* wv    = (const float*)d_in[5];
  const float* wfin  = (const float*)d_in[6];
  const float* bfin  = (const float*)d_in[7];
  const float* gamma = (const float*)d_in[8];
  const float* beta  = (const float*)d_in[9];

  // Workspace layout (bytes), high-water 328 MB with aliasing:
  //   0..8M    : WQT WKT WVT WF (bf16 weights)
  //   8M..72M  : Qin (dead after Q-proj) -> Vb (dead after transpose) -> CTX
  //   72M..136M: Kin (dead after K-proj) -> VTb
  //   136M..200M: Vin (dead after V-proj) -> Pb (32MB bf16 P)
  //   200M..328M: Qb+Kb (dead after scores) -> X (f32 [32768][1024])
  char* ws = (char*)d_ws;
  u16* WQT = (u16*)ws;                     // 2 MB each, [N][K] bf16
  u16* WKT = WQT + 1024 * 1024;
  u16* WVT = WKT + 1024 * 1024;
  u16* WF  = WVT + 1024 * 1024;
  u16* Qin = (u16*)(ws + 8388608);         // 64 MB each, contiguous for cast z-stride
  u16* Kin = Qin + 33554432;
  u16* Vin = Kin + 33554432;
  u16* Qb  = (u16*)(ws + 209715200);       // 200M
  u16* Kb  = Qb + 33554432;                // 264M..328M
  u16* Vb  = Qin;                          // alias: Qin dead after Q-proj
  u16* VTb = Kin;                          // alias: Kin dead after K-proj
  u16* Pb  = Vin;                          // alias: Vin dead after V-proj (32MB used)
  u16* CTX = Qin;                          // alias: Vb dead after transpose_v
  float* X = (float*)(ws + 209715200);     // alias Qb+Kb (dead after scores), 128 MB

  float* out  = (float*)d_out;             // [32768][1024] f32
  float* attn = out + 33554432;            // [64][512][512] f32 (output 1)

  dim3 blk(256);

  wconv_t<<<dim3(32, 32, 3), blk, 0, stream>>>(wq, wk, wv, WQT);
  wconv<<<dim3(1024), blk, 0, stream>>>(wfin, WF);
  cast_bf16<<<dim3(16384, 1, 3), blk, 0, stream>>>(query, key, value, Qin);

  // Projections: [32768,1024] = A(bf16) x Wt(bf16), async16 both operands.
  gemm_bt<0><<<dim3(8, 256, 1), blk, 0, stream>>>(Qin, WQT, Qb, 1024, 1024, 1024, 1024,
                                                  0, 0, 0, nullptr, nullptr, 1.0f);
  gemm_bt<0><<<dim3(8, 256, 1), blk, 0, stream>>>(Kin, WKT, Kb, 1024, 1024, 1024, 1024,
                                                  0, 0, 0, nullptr, nullptr, 1.0f);
  gemm_bt<0><<<dim3(8, 256, 1), blk, 0, stream>>>(Vin, WVT, Vb, 1024, 1024, 1024, 1024,
                                                  0, 0, 0, nullptr, nullptr, 1.0f);

  transpose_v<<<dim3(16, 8, 64), blk, 0, stream>>>(Vb, VTb);

  // Scores: per block z: S = Q_blk x K_blk^T * 0.125 -> d_out attn region (f32)
  gemm_bt<1><<<dim3(4, 4, 64), blk, 0, stream>>>(Qb, Kb, attn, 1024, 1024, 1024, 512,
                                                 524288, 524288, 262144,
                                                 nullptr, nullptr, 0.125f);

  softmax_k<<<dim3(8192), blk, 0, stream>>>(attn, Pb);

  // PV: ctx = P(bf16) x Vt -> bf16
  gemm_bt<0><<<dim3(8, 4, 64), blk, 0, stream>>>(Pb, VTb, CTX, 512, 512, 512, 1024,
                                                 262144, 524288, 524288,
                                                 nullptr, nullptr, 1.0f);

  // Final: x = ctx x WF^T(bt) + b_final + residual(query) -> f32
  gemm_bt<2><<<dim3(8, 256, 1), blk, 0, stream>>>(CTX, WF, X, 1024, 1024, 1024, 1024,
                                                  0, 0, 0, query, bfin, 1.0f);

  layernorm_k<<<dim3(32768), blk, 0, stream>>>(X, gamma, beta, out);
}

// Round 3
// 1112.917 us; speedup vs baseline: 1.1224x; 1.0595x over previous
//
#include <hip/hip_runtime.h>

typedef unsigned short u16;
typedef __bf16 bf16x8 __attribute__((ext_vector_type(8)));
typedef float floatx4 __attribute__((ext_vector_type(4)));
typedef u16 u16x8 __attribute__((ext_vector_type(8)));

// Problem: B=4, S=8192, D=1024, H=16 -> 64 attention blocks of [512 x 1024]
// M_total = 32768 rows.

__device__ __forceinline__ u16 f2bf(float f) {
  union { float f; unsigned u; } x; x.f = f;
  unsigned r = x.u + 0x7FFFu + ((x.u >> 16) & 1u);
  return (u16)(r >> 16);
}

__device__ __forceinline__ void async16(const u16* g, u16* l) {
  __builtin_amdgcn_global_load_lds((const __attribute__((address_space(1))) void*)g,
                                   (__attribute__((address_space(3))) void*)l,
                                   16, 0, 0);
}

// ---------------------------------------------------------------------------
// Weight convert+transpose: W [K=1024][N=1024] f32 -> Wt [N][K] bf16
// ---------------------------------------------------------------------------
__global__ __launch_bounds__(256) void wconv_t(const float* __restrict__ wq,
                                               const float* __restrict__ wk,
                                               const float* __restrict__ wv,
                                               u16* __restrict__ dst0) {
  const float* src = blockIdx.z == 0 ? wq : (blockIdx.z == 1 ? wk : wv);
  u16* dst = dst0 + (size_t)blockIdx.z * 1024 * 1024;
  __shared__ float t[32][33];
  int k0 = blockIdx.y * 32, n0 = blockIdx.x * 32;
  int tid = threadIdx.x;
  int row = tid >> 3, c4 = (tid & 7) * 4;
  float4 v = *(const float4*)&src[(size_t)(k0 + row) * 1024 + n0 + c4];
  t[row][c4 + 0] = v.x; t[row][c4 + 1] = v.y; t[row][c4 + 2] = v.z; t[row][c4 + 3] = v.w;
  __syncthreads();
  ushort4 u;
  u.x = f2bf(t[c4 + 0][row]);
  u.y = f2bf(t[c4 + 1][row]);
  u.z = f2bf(t[c4 + 2][row]);
  u.w = f2bf(t[c4 + 3][row]);
  *(ushort4*)&dst[(size_t)(n0 + row) * 1024 + k0 + c4] = u;
}

// w_final is used as context @ w_final.T -> already [N][K]; plain convert.
__global__ __launch_bounds__(256) void wconv(const float* __restrict__ w, u16* __restrict__ dst) {
  size_t i = ((size_t)blockIdx.x * 256 + threadIdx.x) * 4;
  float4 v = *(const float4*)&w[i];
  ushort4 u; u.x = f2bf(v.x); u.y = f2bf(v.y); u.z = f2bf(v.z); u.w = f2bf(v.w);
  *(ushort4*)&dst[i] = u;
}

// ---------------------------------------------------------------------------
// Cast q/k/v f32 -> bf16 (contiguous dst, z selects array). 8 elems/thread.
// ---------------------------------------------------------------------------
__global__ __launch_bounds__(256) void cast_bf16(const float* __restrict__ q,
                                                 const float* __restrict__ k,
                                                 const float* __restrict__ v,
                                                 u16* __restrict__ dst0) {
  const float* src = blockIdx.z == 0 ? q : (blockIdx.z == 1 ? k : v);
  u16* dst = dst0 + (size_t)blockIdx.z * 33554432;
  size_t i = ((size_t)blockIdx.x * 256 + threadIdx.x) * 8;
  float4 a = *(const float4*)&src[i];
  float4 b = *(const float4*)&src[i + 4];
  u16x8 o;
  o[0] = f2bf(a.x); o[1] = f2bf(a.y); o[2] = f2bf(a.z); o[3] = f2bf(a.w);
  o[4] = f2bf(b.x); o[5] = f2bf(b.y); o[6] = f2bf(b.z); o[7] = f2bf(b.w);
  *(u16x8*)&dst[i] = o;
}

// ---------------------------------------------------------------------------
// Transpose V: per block z: V[512][1024] bf16 -> Vt[1024][512] bf16
// ---------------------------------------------------------------------------
__global__ __launch_bounds__(256) void transpose_v(const u16* __restrict__ V,
                                                   u16* __restrict__ Vt) {
  __shared__ u16 t[64][65];
  const u16* src = V + (size_t)blockIdx.z * 512 * 1024;
  u16* dst = Vt + (size_t)blockIdx.z * 1024 * 512;
  int s0 = blockIdx.y * 64, d0 = blockIdx.x * 64;
  int tid = threadIdx.x;
#pragma unroll
  for (int i = 0; i < 4; ++i) {
    int row = i * 16 + (tid >> 4);
    int c4 = (tid & 15) * 4;
    ushort4 v = *(const ushort4*)&src[(size_t)(s0 + row) * 1024 + d0 + c4];
    t[row][c4 + 0] = v.x; t[row][c4 + 1] = v.y; t[row][c4 + 2] = v.z; t[row][c4 + 3] = v.w;
  }
  __syncthreads();
#pragma unroll
  for (int i = 0; i < 4; ++i) {
    int row = i * 16 + (tid >> 4);   // d index within tile
    int c4 = (tid & 15) * 4;         // s index within tile
    ushort4 u;
    u.x = t[c4 + 0][row]; u.y = t[c4 + 1][row]; u.z = t[c4 + 2][row]; u.w = t[c4 + 3][row];
    *(ushort4*)&dst[(size_t)(d0 + row) * 512 + s0 + c4] = u;
  }
}

// ---------------------------------------------------------------------------
// GEMM, gemm_bt pattern: C[m][n] = sum_k A[m][k] * B[n][k], A and B bf16.
// 128x128 tile, BK=32, 4 waves (2x2), each wave 4x4 tiles of 16x16x32 MFMA.
// T3+T4 minimum 2-phase: double-buffered LDS; stage tile t+1 into the
// alternate buffer BEFORE computing tile t; ONE __syncthreads per tile
// (its vmcnt(0)+lgkmcnt(0) drain lands after the MFMAs -> prefetch overlaps
// compute). Named buffers A0/A1/B0/B1 keep LDS indexing static.
// OMODE: 0 = bf16 store, 1 = fp32*scale store (scores), 2 = fp32 +bias+residual.
// XCD-aware bijective swizzle over the FULL (x,y,z) grid (pow2 gx,gy; nwg%8==0).
// ---------------------------------------------------------------------------
template <int OMODE>
__global__ __launch_bounds__(256, 3) void gemm_bt(
    const u16* __restrict__ Ap, const u16* __restrict__ Bp, void* __restrict__ Cp,
    int K, int lda, int ldb, int ldc,
    int sA, int sB, int sC,
    const float* __restrict__ res, const float* __restrict__ bias, float scale) {
  __shared__ u16 A0[128 * 32];
  __shared__ u16 B0[128 * 32];
  __shared__ u16 A1[128 * 32];
  __shared__ u16 B1[128 * 32];

  const int tid = threadIdx.x;
  const int wave = tid >> 6, lane = tid & 63;
  const int wm = wave >> 1, wn = wave & 1;
  const int quad = lane >> 4, r16 = lane & 15;

  // XCD-aware bijective swizzle (pow2 de-linearize; no integer division).
  const unsigned gx = gridDim.x, gy = gridDim.y;
  const unsigned nwg = gx * gy * gridDim.z;
  unsigned bid = (blockIdx.z * gy + blockIdx.y) * gx + blockIdx.x;
  unsigned nb = (bid & 7u) * (nwg >> 3) + (bid >> 3);
  const unsigned bx = nb & (gx - 1u);
  nb >>= __builtin_ctz(gx);
  const unsigned by = nb & (gy - 1u);
  nb >>= __builtin_ctz(gy);
  const unsigned bz = nb;

  const unsigned m0 = by * 128u;
  const unsigned n0 = bx * 128u;

  const u16* Ab = Ap + (size_t)bz * (unsigned)sA;
  const u16* Bb = Bp + (size_t)bz * (unsigned)sB;

  // Staging addresses: chunk = {wave, wave+4}; lane covers 16 rows x 32 cols.
  const int srow = lane >> 2;          // 0..15
  const int scol = (lane & 3) * 8;     // 0,8,16,24
  const u16* ga = Ab + (size_t)((m0 + wave * 16 + srow) * (unsigned)lda + scol);
  const u16* gb = Bb + (size_t)((n0 + wave * 16 + srow) * (unsigned)ldb + scol);
  const size_t stepA = (size_t)64 * (unsigned)lda;   // chunk c=1 row offset
  const size_t stepB = (size_t)64 * (unsigned)ldb;
  u16* la0 = &A0[wave * 512];          // wave-uniform LDS bases (lane x 16B auto)
  u16* lb0 = &B0[wave * 512];
  u16* la1 = &A1[wave * 512];
  u16* lb1 = &B1[wave * 512];

  floatx4 acc[4][4] = {};

  auto compute = [&](const u16* AS, const u16* BS) {
    bf16x8 af[4], bfr[4];
#pragma unroll
    for (int i = 0; i < 4; ++i)
      af[i] = *(const bf16x8*)&AS[(wm * 64 + i * 16 + r16) * 32 + quad * 8];
#pragma unroll
    for (int j = 0; j < 4; ++j)
      bfr[j] = *(const bf16x8*)&BS[(wn * 64 + j * 16 + r16) * 32 + quad * 8];
#pragma unroll
    for (int i = 0; i < 4; ++i)
#pragma unroll
      for (int j = 0; j < 4; ++j)
        acc[i][j] = __builtin_amdgcn_mfma_f32_16x16x32_bf16(af[i], bfr[j], acc[i][j], 0, 0, 0);
  };

  const int nt = K >> 5;   // tiles of BK=32; even at every call site (32/32/16)

  // prologue: stage tile 0 into buf0
  async16(ga, la0); async16(ga + stepA, la0 + 2048);
  async16(gb, lb0); async16(gb + stepB, lb0 + 2048);
  ga += 32; gb += 32;
  __syncthreads();

  for (int t = 1; t + 1 < nt; t += 2) {
    // stage tile t into buf1, compute tile t-1 from buf0
    async16(ga, la1); async16(ga + stepA, la1 + 2048);
    async16(gb, lb1); async16(gb + stepB, lb1 + 2048);
    ga += 32; gb += 32;
    compute(A0, B0);
    __syncthreads();
    // stage tile t+1 into buf0, compute tile t from buf1
    async16(ga, la0); async16(ga + stepA, la0 + 2048);
    async16(gb, lb0); async16(gb + stepB, lb0 + 2048);
    ga += 32; gb += 32;
    compute(A1, B1);
    __syncthreads();
  }
  // tail: stage last tile (nt-1, odd -> buf1), compute tile nt-2 from buf0
  async16(ga, la1); async16(ga + stepA, la1 + 2048);
  async16(gb, lb1); async16(gb + stepB, lb1 + 2048);
  compute(A0, B0);
  __syncthreads();
  compute(A1, B1);

#pragma unroll
  for (int i = 0; i < 4; ++i) {
    unsigned row = m0 + wm * 64 + i * 16 + quad * 4;
#pragma unroll
    for (int j = 0; j < 4; ++j) {
      unsigned col = n0 + wn * 64 + j * 16 + r16;
#pragma unroll
      for (int r = 0; r < 4; ++r) {
        unsigned idx = (row + r) * (unsigned)ldc + col;
        if constexpr (OMODE == 0) {
          ((u16*)Cp)[(size_t)bz * (unsigned)sC + idx] = f2bf(acc[i][j][r]);
        } else if constexpr (OMODE == 1) {
          ((float*)Cp)[(size_t)bz * (unsigned)sC + idx] = acc[i][j][r] * scale;
        } else {
          float xv = acc[i][j][r] + bias[col] + res[idx];
          ((float*)Cp)[idx] = xv;
        }
      }
    }
  }
}

// ---------------------------------------------------------------------------
// Softmax in place over rows of 512 (one wave per row); also emits bf16 P.
// ---------------------------------------------------------------------------
__global__ __launch_bounds__(256) void softmax_k(float* __restrict__ attn,
                                                 u16* __restrict__ Pb) {
  size_t row = (size_t)blockIdx.x * 4 + (threadIdx.x >> 6);
  int lane = threadIdx.x & 63;
  float* p = attn + row * 512 + lane * 8;
  float4 a = *(const float4*)p;
  float4 b = *(const float4*)(p + 4);
  float m = fmaxf(fmaxf(fmaxf(a.x, a.y), fmaxf(a.z, a.w)),
                  fmaxf(fmaxf(b.x, b.y), fmaxf(b.z, b.w)));
#pragma unroll
  for (int off = 32; off >= 1; off >>= 1) m = fmaxf(m, __shfl_xor(m, off));
  float e[8];
  e[0] = __expf(a.x - m); e[1] = __expf(a.y - m); e[2] = __expf(a.z - m); e[3] = __expf(a.w - m);
  e[4] = __expf(b.x - m); e[5] = __expf(b.y - m); e[6] = __expf(b.z - m); e[7] = __expf(b.w - m);
  float s = e[0] + e[1] + e[2] + e[3] + e[4] + e[5] + e[6] + e[7];
#pragma unroll
  for (int off = 32; off >= 1; off >>= 1) s += __shfl_xor(s, off);
  float inv = 1.0f / s;
  float o[8];
#pragma unroll
  for (int i = 0; i < 8; ++i) o[i] = e[i] * inv;
  float4 oa, ob;
  oa.x = o[0]; oa.y = o[1]; oa.z = o[2]; oa.w = o[3];
  ob.x = o[4]; ob.y = o[5]; ob.z = o[6]; ob.w = o[7];
  *(float4*)p = oa;
  *(float4*)(p + 4) = ob;
  u16x8 pb;
#pragma unroll
  for (int i = 0; i < 8; ++i) pb[i] = f2bf(o[i]);
  *(u16x8*)&Pb[row * 512 + lane * 8] = pb;
}

// ---------------------------------------------------------------------------
// LayerNorm rows of 1024 (one block of 256 per row): out = (x-mean)*rstd*g + b
// ---------------------------------------------------------------------------
__global__ __launch_bounds__(256) void layernorm_k(const float* __restrict__ x,
                                                   const float* __restrict__ gamma,
                                                   const float* __restrict__ beta,
                                                   float* __restrict__ out) {
  size_t row = blockIdx.x;
  int tid = threadIdx.x, lane = tid & 63, wave = tid >> 6;
  float4 v = *(const float4*)&x[row * 1024 + tid * 4];
  float s = v.x + v.y + v.z + v.w;
  float q = v.x * v.x + v.y * v.y + v.z * v.z + v.w * v.w;
#pragma unroll
  for (int off = 32; off >= 1; off >>= 1) {
    s += __shfl_xor(s, off);
    q += __shfl_xor(q, off);
  }
  __shared__ float ss[4], qq[4];
  if (lane == 0) { ss[wave] = s; qq[wave] = q; }
  __syncthreads();
  s = ss[0] + ss[1] + ss[2] + ss[3];
  q = qq[0] + qq[1] + qq[2] + qq[3];
  float mean = s * (1.0f / 1024.0f);
  float var = q * (1.0f / 1024.0f) - mean * mean;
  float rstd = rsqrtf(var + 1e-5f);
  float4 g = *(const float4*)&gamma[tid * 4];
  float4 be = *(const float4*)&beta[tid * 4];
  float4 o;
  o.x = (v.x - mean) * rstd * g.x + be.x;
  o.y = (v.y - mean) * rstd * g.y + be.y;
  o.z = (v.z - mean) * rstd * g.z + be.z;
  o.w = (v.w - mean) * rstd * g.w + be.w;
  *(float4*)&out[row * 1024 + tid * 4] = o;
}

// ---------------------------------------------------------------------------
extern "C" void kernel_launch(void* const* d_in, const int* in_sizes, int n_in,
                              void* d_out, int out_size, void* d_ws, size_t ws_size,
                              hipStream_t stream) {
  const float* query = (const float*)d_in[0];
  const float* key   = (const float*)d_in[1];
  const float* value = (const float*)d_in[2];
  const float* wq    = (const float*)d_in[3];
  const float* wk    = (const float*)d_in[4];
  const float* wv    = (const float*)d_in[5];
  const float* wfin  = (const float*)d_in[6];
  const float* bfin  = (const float*)d_in[7];
  const float* gamma = (const float*)d_in[8];
  const float* beta  = (const float*)d_in[9];

  // Workspace layout (bytes), high-water 328 MB with aliasing:
  //   0..8M    : WQT WKT WVT WF (bf16 weights)
  //   8M..72M  : Qin (dead after Q-proj) -> Vb (dead after transpose) -> CTX
  //   72M..136M: Kin (dead after K-proj) -> VTb
  //   136M..200M: Vin (dead after V-proj) -> Pb (32MB bf16 P)
  //   200M..328M: Qb+Kb (dead after scores) -> X (f32 [32768][1024])
  char* ws = (char*)d_ws;
  u16* WQT = (u16*)ws;                     // 2 MB each, [N][K] bf16
  u16* WKT = WQT + 1024 * 1024;
  u16* WVT = WKT + 1024 * 1024;
  u16* WF  = WVT + 1024 * 1024;
  u16* Qin = (u16*)(ws + 8388608);         // 64 MB each, contiguous for cast z-stride
  u16* Kin = Qin + 33554432;
  u16* Vin = Kin + 33554432;
  u16* Qb  = (u16*)(ws + 209715200);       // 200M
  u16* Kb  = Qb + 33554432;                // 264M..328M
  u16* Vb  = Qin;                          // alias: Qin dead after Q-proj
  u16* VTb = Kin;                          // alias: Kin dead after K-proj
  u16* Pb  = Vin;                          // alias: Vin dead after V-proj (32MB used)
  u16* CTX = Qin;                          // alias: Vb dead after transpose_v
  float* X = (float*)(ws + 209715200);     // alias Qb+Kb (dead after scores), 128 MB

  float* out  = (float*)d_out;             // [32768][1024] f32
  float* attn = out + 33554432;            // [64][512][512] f32 (output 1)

  dim3 blk(256);

  wconv_t<<<dim3(32, 32, 3), blk, 0, stream>>>(wq, wk, wv, WQT);
  wconv<<<dim3(1024), blk, 0, stream>>>(wfin, WF);
  cast_bf16<<<dim3(16384, 1, 3), blk, 0, stream>>>(query, key, value, Qin);

  // Projections: [32768,1024] = A(bf16) x Wt(bf16), async16 both operands.
  gemm_bt<0><<<dim3(8, 256, 1), blk, 0, stream>>>(Qin, WQT, Qb, 1024, 1024, 1024, 1024,
                                                  0, 0, 0, nullptr, nullptr, 1.0f);
  gemm_bt<0><<<dim3(8, 256, 1), blk, 0, stream>>>(Kin, WKT, Kb, 1024, 1024, 1024, 1024,
                                                  0, 0, 0, nullptr, nullptr, 1.0f);
  gemm_bt<0><<<dim3(8, 256, 1), blk, 0, stream>>>(Vin, WVT, Vb, 1024, 1024, 1024, 1024,
                                                  0, 0, 0, nullptr, nullptr, 1.0f);

  transpose_v<<<dim3(16, 8, 64), blk, 0, stream>>>(Vb, VTb);

  // Scores: per block z: S = Q_blk x K_blk^T * 0.125 -> d_out attn region (f32)
  gemm_bt<1><<<dim3(4, 4, 64), blk, 0, stream>>>(Qb, Kb, attn, 1024, 1024, 1024, 512,
                                                 524288, 524288, 262144,
                                                 nullptr, nullptr, 0.125f);

  softmax_k<<<dim3(8192), blk, 0, stream>>>(attn, Pb);

  // PV: ctx = P(bf16) x Vt -> bf16
  gemm_bt<0><<<dim3(8, 4, 64), blk, 0, stream>>>(Pb, VTb, CTX, 512, 512, 512, 1024,
                                                 262144, 524288, 524288,
                                                 nullptr, nullptr, 1.0f);

  // Final: x = ctx x WF^T(bt) + b_final + residual(query) -> f32
  gemm_bt<2><<<dim3(8, 256, 1), blk, 0, stream>>>(CTX, WF, X, 1024, 1024, 1024, 1024,
                                                  0, 0, 0, query, bfin, 1.0f);

  layernorm_k<<<dim3(32768), blk, 0, stream>>>(X, gamma, beta, out);
}